// Round 10
// baseline (417.351 us; speedup 1.0000x reference)
//
#include <hip/hip_runtime.h>

// bf16 stored as raw ushort everywhere; MFMA consumes __bf16 vectors.
typedef unsigned short u16;
using bf16x8  = __attribute__((ext_vector_type(8))) __bf16;
using floatx4 = __attribute__((ext_vector_type(4))) float;

__device__ __forceinline__ u16 f2bf(float f) {
  unsigned int u = __builtin_bit_cast(unsigned int, f);
  u += 0x7fffu + ((u >> 16) & 1u);          // round-to-nearest-even
  return (u16)(u >> 16);
}
__device__ __forceinline__ float bf2f(u16 h) {
  unsigned int u = ((unsigned int)h) << 16;
  return __builtin_bit_cast(float, u);
}
__device__ __forceinline__ float fast_exp2(float x) {
#if __has_builtin(__builtin_amdgcn_exp2f)
  return __builtin_amdgcn_exp2f(x);        // v_exp_f32 directly
#else
  return exp2f(x);
#endif
}

#define AS1(p) ((const __attribute__((address_space(1))) void*)(p))
#define AS3(p) ((__attribute__((address_space(3))) void*)(p))

// ---- GEMM core: verified m97 structure, BK=32 ONLY (R5: BK=64 regressed).
// KSTEP      : acc = mfma(af, bfv) -> thread's 4 regs = 4 ROWS (m89 layout)
// KSTEP_SWAP : acc = mfma(bfv, af) -> transposed: 4 regs = 4 consecutive COLS
//              (row = lane&15) -> vectorized ushort4/float4 epilogue stores
//              (R8-verified).
#define GEMM_PROLOGUE_AT(bmv, bnv)                                           \
  __shared__ u16 As[128 * 32];                                               \
  __shared__ u16 Bs[128 * 32];                                               \
  const int tid  = threadIdx.x;                                              \
  const int wave = tid >> 6, lane = tid & 63;                                \
  const int wm = (wave >> 1) * 64, wn = (wave & 1) * 64;                     \
  const long bm = (bmv), bn = (bnv);                                         \
  floatx4 acc[4][4] = {};                                                    \
  const int srow = lane >> 2;                                                \
  const int scol = (lane & 3) * 8;                                           \
  const int c0 = wave * 2, c1 = c0 + 1;                                      \
  const int fr = lane & 15;                                                  \
  const int kq = (lane >> 4) * 8;                                            \
  const int oc = (lane >> 4) * 4;   /* swapped layout: col quad offset */

#define GEMM_PROLOGUE() GEMM_PROLOGUE_AT((long)blockIdx.y * 128, (long)blockIdx.x * 128)

#define GEMM_STAGE(Ab, Bb, K, k0)                                            \
    __syncthreads();                                                         \
    __builtin_amdgcn_global_load_lds(AS1(Ab + (long)(c0*16 + srow)*K + k0 + scol), AS3(As + c0*512), 16, 0, 0); \
    __builtin_amdgcn_global_load_lds(AS1(Ab + (long)(c1*16 + srow)*K + k0 + scol), AS3(As + c1*512), 16, 0, 0); \
    __builtin_amdgcn_global_load_lds(AS1(Bb + (long)(c0*16 + srow)*K + k0 + scol), AS3(Bs + c0*512), 16, 0, 0); \
    __builtin_amdgcn_global_load_lds(AS1(Bb + (long)(c1*16 + srow)*K + k0 + scol), AS3(Bs + c1*512), 16, 0, 0); \
    __syncthreads();                                                         \
    bf16x8 af[4], bfv[4];                                                    \
    _Pragma("unroll")                                                        \
    for (int mi = 0; mi < 4; ++mi)                                           \
      af[mi] = *(const bf16x8*)(As + (wm + mi*16 + fr)*32 + kq);             \
    _Pragma("unroll")                                                        \
    for (int ni = 0; ni < 4; ++ni)                                           \
      bfv[ni] = *(const bf16x8*)(Bs + (wn + ni*16 + fr)*32 + kq);

#define GEMM_KSTEP(Ab, Bb, K, k0)                                            \
  {                                                                          \
    GEMM_STAGE(Ab, Bb, K, k0)                                                \
    _Pragma("unroll")                                                        \
    for (int mi = 0; mi < 4; ++mi)                                           \
      _Pragma("unroll")                                                      \
      for (int ni = 0; ni < 4; ++ni)                                         \
        acc[mi][ni] = __builtin_amdgcn_mfma_f32_16x16x32_bf16(af[mi], bfv[ni], acc[mi][ni], 0, 0, 0); \
  }

#define GEMM_KSTEP_SWAP(Ab, Bb, K, k0)                                       \
  {                                                                          \
    GEMM_STAGE(Ab, Bb, K, k0)                                                \
    _Pragma("unroll")                                                        \
    for (int mi = 0; mi < 4; ++mi)                                           \
      _Pragma("unroll")                                                      \
      for (int ni = 0; ni < 4; ++ni)                                         \
        acc[mi][ni] = __builtin_amdgcn_mfma_f32_16x16x32_bf16(bfv[ni], af[mi], acc[mi][ni], 0, 0, 0); \
  }

// Final projection: C = A*Bt^T + bias, fp32 out, swapped epilogue (float4).
__global__ __launch_bounds__(256) void gemm_bt(
    const u16* __restrict__ A, const u16* __restrict__ Bt,
    float* __restrict__ Cout, const float* __restrict__ bias, int N, int K)
{
  GEMM_PROLOGUE();
  const u16* Ab = A + bm * K;
  const u16* Bb = Bt + bn * K;
  for (int k0 = 0; k0 < K; k0 += 32) GEMM_KSTEP_SWAP(Ab, Bb, K, k0);

#pragma unroll
  for (int mi = 0; mi < 4; ++mi) {
    long row = bm + wm + mi*16 + fr;
#pragma unroll
    for (int ni = 0; ni < 4; ++ni) {
      long colb = bn + wn + ni*16 + oc;
      float4 bv4 = *(const float4*)(bias + colb);
      float4 o;
      o.x = acc[mi][ni][0] + bv4.x;
      o.y = acc[mi][ni][1] + bv4.y;
      o.z = acc[mi][ni][2] + bv4.z;
      o.w = acc[mi][ni][3] + bv4.w;
      *(float4*)(Cout + row * N + colb) = o;
    }
  }
}

// Batch-combined QK^T + unnormalized exp, XCD-swizzled, swapped epilogue.
// Grid (32,32,2) = 2048 blocks. lin%8 = XCD; batch = xcd>>2; each XCD owns an
// 8-row by-band of one batch, sweeps bx in 8-wide tiles (4MB L2 window).
// P[b] = 2^(alpha2 * qk) bf16 (ushort4 stores) where alpha2 = scale*log2(e)
// -- identical to exp(scale*qk), one v_mul fewer per element.
// lpartT[b][row][64] fp32 partial denominators.
__global__ __launch_bounds__(256) void gemm_qk_exp(
    const u16* __restrict__ q, const u16* __restrict__ k,
    u16* __restrict__ probs, float* __restrict__ lpartT, float alpha2)
{
  const int N = 4096, K = 1024;
  const int lin = blockIdx.x + (blockIdx.y << 5) + (blockIdx.z << 10);
  const int xcd = lin & 7, j = lin >> 3;          // j in [0,256)
  const long b = xcd >> 2;
  const int band = (xcd & 3) * 8;                 // by-band base
  const int t = j >> 6, w = j & 63;               // 4 bx-tiles of 64 blocks
  const int bx = t * 8 + (w & 7);                 // [0,32)
  const int by = band + (w >> 3);                 // [0,32)

  const u16* A  = q + b * 4096 * 1024;
  const u16* Bt = k + b * 4096 * 1024;
  u16* P = probs + b * 4096L * 4096;
  float* lp = lpartT + b * 4096 * 64;

  GEMM_PROLOGUE_AT((long)by * 128, (long)bx * 128);
  const u16* Ab = A + bm * K;
  const u16* Bb = Bt + bn * K;
  for (int k0 = 0; k0 < K; k0 += 32) GEMM_KSTEP_SWAP(Ab, Bb, K, k0);

  // swapped layout: q-row = bm+wm+mi*16+fr; k-cols = bn+wn+ni*16+oc+{0..3}
  float rowsum[4] = {0.f, 0.f, 0.f, 0.f};
#pragma unroll
  for (int mi = 0; mi < 4; ++mi) {
    long row = bm + wm + mi*16 + fr;
#pragma unroll
    for (int ni = 0; ni < 4; ++ni) {
      long colb = bn + wn + ni*16 + oc;
      float e0 = fast_exp2(acc[mi][ni][0] * alpha2);
      float e1 = fast_exp2(acc[mi][ni][1] * alpha2);
      float e2 = fast_exp2(acc[mi][ni][2] * alpha2);
      float e3 = fast_exp2(acc[mi][ni][3] * alpha2);
      rowsum[mi] += (e0 + e1) + (e2 + e3);
      ushort4 o;
      o.x = f2bf(e0); o.y = f2bf(e1); o.z = f2bf(e2); o.w = f2bf(e3);
      *(ushort4*)(P + row * N + colb) = o;
    }
  }
  // lanes {l, l^16, l^32, l^48} share fr (same q-row): reduce over quads.
  const long cg = bx * 2 + (wn >> 6);
#pragma unroll
  for (int mi = 0; mi < 4; ++mi) {
    float s = rowsum[mi];
    s += __shfl_xor(s, 16); s += __shfl_xor(s, 32);
    if (lane < 16)
      lp[(bm + wm + mi*16 + lane) * 64 + cg] = s;
  }
}

// Fused QKV projection, XCD by-band swizzle: grid (24,64) = 1536 blocks,
// lin%8 = XCD; each XCD owns by in [xcd*8, xcd*8+8) and sweeps all 24 bx ->
// each xb row-stripe is fetched by exactly one XCD (R9 FETCH showed ~4x
// refetch of xb without this). Block-uniform region: bn<2048 -> q/k
// (swapped epilogue, ushort4); bn>=2048 -> vT[b][d][s] (original order).
__global__ __launch_bounds__(256) void gemm_qkv(
    const u16* __restrict__ A, const u16* __restrict__ Bt,
    u16* __restrict__ qb, u16* __restrict__ kb, u16* __restrict__ vT,
    const float* __restrict__ bq, const float* __restrict__ bk,
    const float* __restrict__ bv)
{
  const int K = 1024;
  const int lin = blockIdx.x + blockIdx.y * 24;   // [0,1536)
  const int xcd = lin & 7, j = lin >> 3;          // j in [0,192)
  const int byl = j / 24, bx = j - byl * 24;      // byl [0,8), bx [0,24)
  const int by = xcd * 8 + byl;                   // [0,64)

  GEMM_PROLOGUE_AT((long)by * 128, (long)bx * 128);
  const u16* Ab = A + bm * K;
  const u16* Bb = Bt + bn * K;

  if (bn < 2048) {
    for (int k0 = 0; k0 < K; k0 += 32) GEMM_KSTEP_SWAP(Ab, Bb, K, k0);
    u16* C = (bn < 1024) ? qb : kb;
    const float* bias = (bn < 1024) ? bq : bk;
#pragma unroll
    for (int mi = 0; mi < 4; ++mi) {
      long row = bm + wm + mi*16 + fr;
#pragma unroll
      for (int ni = 0; ni < 4; ++ni) {
        long colg = bn + wn + ni*16 + oc;
        long cc = colg & 1023;
        float4 bv4 = *(const float4*)(bias + cc);
        ushort4 o;
        o.x = f2bf(acc[mi][ni][0] + bv4.x);
        o.y = f2bf(acc[mi][ni][1] + bv4.y);
        o.z = f2bf(acc[mi][ni][2] + bv4.z);
        o.w = f2bf(acc[mi][ni][3] + bv4.w);
        *(ushort4*)(C + row * 1024 + cc) = o;
      }
    }
  } else {
    for (int k0 = 0; k0 < K; k0 += 32) GEMM_KSTEP(Ab, Bb, K, k0);
    const int orow = (lane >> 4) * 4;
    const int ocol = lane & 15;
#pragma unroll
    for (int ni = 0; ni < 4; ++ni) {
      long col = bn + wn + ni*16 + ocol;
      float bvv = bv[col - 2048];
#pragma unroll
      for (int mi = 0; mi < 4; ++mi) {
        long row = bm + wm + mi*16 + orow;
        long b_ = row >> 12, s = row & 4095, d = col - 2048;
        ushort4 o;
        o.x = f2bf(acc[mi][ni][0] + bvv);
        o.y = f2bf(acc[mi][ni][1] + bvv);
        o.z = f2bf(acc[mi][ni][2] + bvv);
        o.w = f2bf(acc[mi][ni][3] + bvv);
        *(ushort4*)(vT + b_ * (1024L * 4096) + d * 4096L + s) = o;
      }
    }
  }
}

// Batch-combined PV split-K=2, bf16 partials, XCD-pair mapping (R7-proven:
// each (batch,split) K-slice owned by one XCD pair; odd/even by-stripes
// alternate -> each probs A-stripe fetched by exactly one XCD).
// Grid (8,32,4) = 1024 blocks = 4/CU; K=2048/block = 64 iters.
__global__ __launch_bounds__(256) void gemm_pv_splitk(
    const u16* __restrict__ probs, const u16* __restrict__ vT,
    u16* __restrict__ pA, u16* __restrict__ pB)
{
  const int N = 1024, K = 4096, Ks = 2048;
  const int lin = blockIdx.x + (blockIdx.y << 3) + (blockIdx.z << 8);
  const int xcd = lin & 7, j = lin >> 3;          // j in [0,128)
  const int slice = xcd >> 1, half = xcd & 1;
  const long b = slice >> 1;
  const int sp = slice & 1;
  const int bx = j & 7;                           // [0,8)
  const int by = (j >> 3) * 2 + half;             // [0,32)

  const u16* A  = probs + b * 4096L * 4096;
  const u16* Bt = vT + b * 1024L * 4096;
  u16* part = (b ? pB : pA) + (long)sp * 4096 * 1024;

  GEMM_PROLOGUE_AT((long)by * 128, (long)bx * 128);
  const u16* Ab = A + bm * K;
  const u16* Bb = Bt + bn * K;
  const int kbeg = sp * Ks, kend = kbeg + Ks;
  for (int k0 = kbeg; k0 < kend; k0 += 32) GEMM_KSTEP_SWAP(Ab, Bb, K, k0);

#pragma unroll
  for (int mi = 0; mi < 4; ++mi) {
    long row = bm + wm + mi*16 + fr;
#pragma unroll
    for (int ni = 0; ni < 4; ++ni) {
      long colb = bn + wn + ni*16 + oc;
      ushort4 o;
      o.x = f2bf(acc[mi][ni][0]);
      o.y = f2bf(acc[mi][ni][1]);
      o.z = f2bf(acc[mi][ni][2]);
      o.w = f2bf(acc[mi][ni][3]);
      *(ushort4*)(part + row * N + colb) = o;
    }
  }
}

// Combined reduce + softmax-normalize: grid (4096 rows, 2 batches).
// Wave 0 reads the row's 64 lpartT entries (coalesced 256B), shuffle-sums,
// broadcasts; out[b][row] = (s0+s1)/l as bf16 (partials are bf16).
__global__ __launch_bounds__(256) void reduce2_div_row(
    const u16* __restrict__ pA, const u16* __restrict__ pB,
    const float* __restrict__ lpartT, u16* __restrict__ ob)
{
  const int row = blockIdx.x;           // [0,4096)
  const long b = blockIdx.y;
  const int tid = threadIdx.x;
  const u16* part = b ? pB : pA;
  const float* lp = lpartT + b * 4096 * 64;
  __shared__ float sl;
  if (tid < 64) {
    float s = lp[(long)row * 64 + tid];
#pragma unroll
    for (int off = 32; off; off >>= 1) s += __shfl_down(s, off);
    if (tid == 0) sl = s;
  }
  __syncthreads();
  const float inv = 1.0f / sl;
  const long base = (long)row * 1024 + tid * 4;
  ushort4 p0 = *(const ushort4*)(part + base);
  ushort4 p1 = *(const ushort4*)(part + 4096L * 1024 + base);
  ushort4 o;
  o.x = f2bf((bf2f(p0.x) + bf2f(p1.x)) * inv);
  o.y = f2bf((bf2f(p0.y) + bf2f(p1.y)) * inv);
  o.z = f2bf((bf2f(p0.z) + bf2f(p1.z)) * inv);
  o.w = f2bf((bf2f(p0.w) + bf2f(p1.w)) * inv);
  *(ushort4*)(ob + b * 4096L * 1024 + base) = o;
}

// Fused prep: blocks [0,8192) cast x (fp32->bf16, float4); blocks
// [8192,12288) transpose+cast the 4 weight matrices (z = (blk-8192)>>10).
__global__ __launch_bounds__(256) void prep(
    const float* __restrict__ x, u16* __restrict__ xb,
    const float* __restrict__ W0, const float* __restrict__ W1,
    const float* __restrict__ W2, const float* __restrict__ W3,
    u16* __restrict__ O0, u16* __restrict__ O1,
    u16* __restrict__ O2, u16* __restrict__ O3)
{
  __shared__ float tile[32][33];
  int blk = blockIdx.x;
  if (blk < 8192) {
    int i = blk * 256 + threadIdx.x;      // 2M float4s
    float4 f = ((const float4*)x)[i];
    ushort4 o;
    o.x = f2bf(f.x); o.y = f2bf(f.y); o.z = f2bf(f.z); o.w = f2bf(f.w);
    ((ushort4*)xb)[i] = o;
  } else {
    blk -= 8192;
    const int z = blk >> 10, t = blk & 1023;
    const float* in = (z == 0) ? W0 : (z == 1) ? W1 : (z == 2) ? W2 : W3;
    u16* outp = (z == 0) ? O0 : (z == 1) ? O1 : (z == 2) ? O2 : O3;
    const int bx = (t & 31) * 32, by = (t >> 5) * 32;
    const int tx = threadIdx.x & 31, ty = threadIdx.x >> 5;   // 32 x 8
    for (int i = ty; i < 32; i += 8)
      tile[i][tx] = in[(long)(by + i) * 1024 + bx + tx];
    __syncthreads();
    for (int i = ty; i < 32; i += 8)
      outp[(long)(bx + i) * 1024 + by + tx] = f2bf(tile[tx][i]);
  }
}

extern "C" void kernel_launch(void* const* d_in, const int* in_sizes, int n_in,
                              void* d_out, int out_size, void* d_ws, size_t ws_size,
                              hipStream_t stream) {
  const float* x  = (const float*)d_in[0];
  const float* Wq = (const float*)d_in[1];
  const float* bq = (const float*)d_in[2];
  const float* Wk = (const float*)d_in[3];
  const float* bk = (const float*)d_in[4];
  const float* Wv = (const float*)d_in[5];
  const float* bv = (const float*)d_in[6];
  const float* Wo = (const float*)d_in[7];
  const float* bo = (const float*)d_in[8];
  float* out = (float*)d_out;

  const int B = 2, S = 4096, D = 1024;
  const long MS = (long)B * S;  // 8192
  const long MB = 1L << 20;

  // ---- workspace layout (top usage 168 MiB; ws_size >= 168 MiB proven) ----
  //  [0,16M)    qb  bf16 [8192,1024]   -- dead after QK_exp; reused as
  //                                       PV bf16 partials batch0 [2][4096][1024]
  //  [16,32M)   kb  bf16 [8192,1024]
  //  [32,48M)   vT  bf16 [B][1024][4096]
  //  [48,64M)   xb  bf16 [8192,1024]   -- aliased with ob (xb dead before PV)
  //  [64,72M)   WqkvT bf16 [3072,1024] + WoT bf16 [1024,1024]
  //  [72,136M)  probs bf16 [B][4096][4096]  (both batches)
  //  [136,168M) PV bf16 partials batch1 [2][4096][1024] (16M used of 32M)
  // d_out (32MB fp32, dead until final proj) hosts lpartT [B][4096][64] fp32.
  char* w = (char*)d_ws;
  u16* qb  = (u16*)(w);
  u16* kb  = (u16*)(w + 16 * MB);
  u16* vT  = (u16*)(w + 32 * MB);
  u16* xb  = (u16*)(w + 48 * MB);
  u16* ob  = xb;                        // alias: xb dead before ob written
  u16* WqkvT = (u16*)(w + 64 * MB);
  u16* WoT = WqkvT + 3072L * 1024;
  u16* probs = (u16*)(w + 72 * MB);
  u16* partA = (u16*)(w);               // over qb, dead after QK_exp
  u16* partB = (u16*)(w + 136 * MB);
  float* lpartT = (float*)d_out;        // [2][4096][64] fp32 = 2MB

  // 1. fused prep: cast x + transpose/cast all 4 weights
  prep<<<dim3(8192 + 4096), 256, 0, stream>>>(
      x, xb, Wq, Wk, Wv, Wo,
      WqkvT, WqkvT + 1024L * 1024, WqkvT + 2048L * 1024, WoT);

  // 2. fused QKV projection: grid (24,64) = 1536 blocks, XCD by-band swizzle
  gemm_qkv<<<dim3(3 * D / 128, MS / 128), 256, 0, stream>>>(
      xb, WqkvT, qb, kb, vT, bq, bk, bv);

  // 3. attention, both batches per launch (XCD-swizzled kernels)
  const float scale2 = 0.125f * 1.44269504f;  // (1/sqrt(64)) * log2(e)
  gemm_qk_exp<<<dim3(S / 128, S / 128, B), 256, 0, stream>>>(
      qb, kb, probs, lpartT, scale2);
  // qb now dead -> partA overlays it
  gemm_pv_splitk<<<dim3(D / 128, S / 128, 4), 256, 0, stream>>>(
      probs, vT, partA, partB);
  reduce2_div_row<<<dim3(S, B), 256, 0, stream>>>(partA, partB, lpartT, ob);

  // 4. final projection -> fp32 d_out (overwrites lpartT scratch)
  gemm_bt<<<dim3(D / 128, MS / 128), 256, 0, stream>>>(ob, WoT, out, bo, D, D);
}